// Round 1
// baseline (521.390 us; speedup 1.0000x reference)
//
#include <hip/hip_runtime.h>

// ---------------------------------------------------------------------------
// 2-layer GCN: z = A_hat (relu(A_hat (X W1) + b1)) W2 + b2
// A_hat = D^-1/2 (A + I) D^-1/2, deg on dst incl. self-loops.
// Strategy: build CSR-by-dst once (histogram + scan + cursor fill, norm
// precomputed per edge slot), transform-then-aggregate for both layers.
// Aggregation: block-per-node, thread-per-dim -> coalesced gathers, no atomics.
// ---------------------------------------------------------------------------

#define KDIM 128

__global__ void init_counts(int* counts, int* cursor, int n) {
    int i = blockIdx.x * blockDim.x + threadIdx.x;
    int stride = gridDim.x * blockDim.x;
    for (; i < n; i += stride) { counts[i] = 0; cursor[i] = 0; }
}

__global__ void count_kernel(const int* __restrict__ dst, int* __restrict__ counts, int e) {
    int i = blockIdx.x * blockDim.x + threadIdx.x;
    int stride = gridDim.x * blockDim.x;
    for (; i < e; i += stride) atomicAdd(&counts[dst[i]], 1);
}

__global__ void dinv_kernel(const int* __restrict__ counts, float* __restrict__ dinv, int n) {
    int i = blockIdx.x * blockDim.x + threadIdx.x;
    int stride = gridDim.x * blockDim.x;
    for (; i < n; i += stride) dinv[i] = rsqrtf((float)(counts[i] + 1));  // +1 self loop
}

// --- 3-kernel exclusive scan over counts -> offsets -------------------------
__global__ void scan_partial(const int* __restrict__ counts, int* __restrict__ local,
                             int* __restrict__ bsums, int n) {
    __shared__ int ld[1024];
    __shared__ int ts[256];
    const int t = threadIdx.x;
    const int base = blockIdx.x * 1024;
    for (int j = t; j < 1024; j += 256) ld[j] = (base + j < n) ? counts[base + j] : 0;
    __syncthreads();
    int a0 = ld[4*t], a1 = ld[4*t+1], a2 = ld[4*t+2], a3 = ld[4*t+3];
    int sum = a0 + a1 + a2 + a3;
    ts[t] = sum;
    for (int off = 1; off < 256; off <<= 1) {
        __syncthreads();
        int v = (t >= off) ? ts[t - off] : 0;
        __syncthreads();
        ts[t] += v;
    }
    __syncthreads();
    int excl = ts[t] - sum;  // exclusive prefix of this thread's group
    if (base + 4*t + 0 < n) local[base + 4*t + 0] = excl;
    if (base + 4*t + 1 < n) local[base + 4*t + 1] = excl + a0;
    if (base + 4*t + 2 < n) local[base + 4*t + 2] = excl + a0 + a1;
    if (base + 4*t + 3 < n) local[base + 4*t + 3] = excl + a0 + a1 + a2;
    if (t == 255) bsums[blockIdx.x] = ts[255];
}

__global__ void scan_bsums(int* __restrict__ bsums, int nb) {
    __shared__ int ts[256];
    const int t = threadIdx.x;
    int v = (t < nb) ? bsums[t] : 0;
    ts[t] = v;
    for (int off = 1; off < 256; off <<= 1) {
        __syncthreads();
        int u = (t >= off) ? ts[t - off] : 0;
        __syncthreads();
        ts[t] += u;
    }
    __syncthreads();
    if (t < nb) bsums[t] = ts[t] - v;  // exclusive
}

__global__ void scan_add(int* __restrict__ offs, const int* __restrict__ bsums, int n, int e_total) {
    int i = blockIdx.x * blockDim.x + threadIdx.x;
    int stride = gridDim.x * blockDim.x;
    for (; i < n; i += stride) offs[i] += bsums[i >> 10];
    if (blockIdx.x == 0 && threadIdx.x == 0) offs[n] = e_total;
}

__global__ void fill_kernel(const int* __restrict__ src, const int* __restrict__ dst,
                            const int* __restrict__ offs, int* __restrict__ cursor,
                            const float* __restrict__ dinv,
                            int* __restrict__ csr_src, float* __restrict__ csr_norm, int e) {
    int i = blockIdx.x * blockDim.x + threadIdx.x;
    int stride = gridDim.x * blockDim.x;
    for (; i < e; i += stride) {
        int s = src[i], d = dst[i];
        int pos = offs[d] + atomicAdd(&cursor[d], 1);
        csr_src[pos] = s;
        csr_norm[pos] = dinv[s] * dinv[d];
    }
}

// --- dense matmul: out[n x DOUT] = x[n x 128] @ W[128 x DOUT] ---------------
template<int ROWS, int DOUT>
__global__ __launch_bounds__((ROWS/4)*(DOUT/4))
void matmul_kernel(const float* __restrict__ x, const float* __restrict__ W,
                   float* __restrict__ out, int n) {
    constexpr int K = KDIM;
    constexpr int TPB = (ROWS/4) * (DOUT/4);
    __shared__ float xs[ROWS][K];
    __shared__ float ws[K][DOUT];
    const int tid = threadIdx.x;
    const int row0 = blockIdx.x * ROWS;

    for (int idx = tid; idx < K*DOUT/4; idx += TPB)
        ((float4*)ws)[idx] = ((const float4*)W)[idx];
    for (int idx = tid; idx < ROWS*K/4; idx += TPB) {
        int r = idx / (K/4);
        int row = row0 + r;
        float4 v = (row < n) ? ((const float4*)x)[(size_t)row*(K/4) + (idx % (K/4))]
                             : make_float4(0.f, 0.f, 0.f, 0.f);
        ((float4*)xs)[idx] = v;
    }
    __syncthreads();

    const int tc = tid % (DOUT/4);
    const int tr = tid / (DOUT/4);
    float acc[4][4] = {};
    #pragma unroll 4
    for (int k = 0; k < K; k += 4) {
        float xa[4][4], wb[4][4];
        #pragma unroll
        for (int r = 0; r < 4; ++r) {
            float4 v = *(const float4*)&xs[tr*4 + r][k];
            xa[r][0] = v.x; xa[r][1] = v.y; xa[r][2] = v.z; xa[r][3] = v.w;
        }
        #pragma unroll
        for (int kk = 0; kk < 4; ++kk) {
            float4 v = *(const float4*)&ws[k + kk][tc*4];
            wb[kk][0] = v.x; wb[kk][1] = v.y; wb[kk][2] = v.z; wb[kk][3] = v.w;
        }
        #pragma unroll
        for (int r = 0; r < 4; ++r)
            #pragma unroll
            for (int kk = 0; kk < 4; ++kk)
                #pragma unroll
                for (int c = 0; c < 4; ++c)
                    acc[r][c] += xa[r][kk] * wb[kk][c];
    }
    #pragma unroll
    for (int r = 0; r < 4; ++r) {
        int row = row0 + tr*4 + r;
        if (row < n) {
            float4 v = make_float4(acc[r][0], acc[r][1], acc[r][2], acc[r][3]);
            *(float4*)&out[(size_t)row*DOUT + tc*4] = v;
        }
    }
}

// --- aggregation, D=128: one block (128 thr) per node -----------------------
__global__ __launch_bounds__(128)
void agg128_kernel(const float* __restrict__ xw, const int* __restrict__ offs,
                   const int* __restrict__ csr_src, const float* __restrict__ csr_norm,
                   const float* __restrict__ dinv, const float* __restrict__ bias,
                   float* __restrict__ out, int n, int do_relu) {
    const int i = blockIdx.x;
    const int d = threadIdx.x;
    const float di = dinv[i];
    float acc = xw[(size_t)i*128 + d] * (di * di);   // self-loop
    const int e0 = offs[i], e1 = offs[i + 1];
    for (int e = e0; e < e1; ++e) {
        int s = csr_src[e];
        float nr = csr_norm[e];
        acc += xw[(size_t)s*128 + d] * nr;
    }
    acc += bias[d];
    if (do_relu) acc = fmaxf(acc, 0.f);
    out[(size_t)i*128 + d] = acc;
}

// --- aggregation, D=32: 4 nodes per 128-thread block ------------------------
__global__ __launch_bounds__(128)
void agg32_kernel(const float* __restrict__ xw, const int* __restrict__ offs,
                  const int* __restrict__ csr_src, const float* __restrict__ csr_norm,
                  const float* __restrict__ dinv, const float* __restrict__ bias,
                  float* __restrict__ out, int n) {
    const int q = threadIdx.x >> 5;
    const int d = threadIdx.x & 31;
    const int i = blockIdx.x * 4 + q;
    if (i >= n) return;
    const float di = dinv[i];
    float acc = xw[(size_t)i*32 + d] * (di * di);
    const int e0 = offs[i], e1 = offs[i + 1];
    for (int e = e0; e < e1; ++e) {
        int s = csr_src[e];
        float nr = csr_norm[e];
        acc += xw[(size_t)s*32 + d] * nr;
    }
    acc += bias[d];
    out[(size_t)i*32 + d] = acc;
}

extern "C" void kernel_launch(void* const* d_in, const int* in_sizes, int n_in,
                              void* d_out, int out_size, void* d_ws, size_t ws_size,
                              hipStream_t stream) {
    const int n = in_sizes[0] / KDIM;      // 100000
    const int e = in_sizes[1] / 2;         // 1600000

    const float* x  = (const float*)d_in[0];
    const int*   ei = (const int*)d_in[1];
    const int*   src = ei;
    const int*   dst = ei + e;
    const float* W1 = (const float*)d_in[2];
    const float* b1 = (const float*)d_in[3];
    const float* W2 = (const float*)d_in[4];
    const float* b2 = (const float*)d_in[5];
    float* out = (float*)d_out;

    // workspace carve (256B aligned)
    char* p = (char*)d_ws;
    auto alloc = [&](size_t bytes) { char* q = p; p += (bytes + 255) & ~(size_t)255; return q; };
    float* dinv     = (float*)alloc((size_t)n * 4);
    int*   counts   = (int*)  alloc((size_t)n * 4);
    int*   cursor   = (int*)  alloc((size_t)n * 4);
    int*   offs     = (int*)  alloc((size_t)(n + 1) * 4);
    int*   bsums    = (int*)  alloc(1024 * 4);
    int*   csr_src  = (int*)  alloc((size_t)e * 4);
    float* csr_norm = (float*)alloc((size_t)e * 4);
    float* xw1      = (float*)alloc((size_t)n * 128 * 4);
    float* h        = (float*)alloc((size_t)n * 128 * 4);
    float* xw2      = (float*)alloc((size_t)n * 32 * 4);

    const int nb_scan = (n + 1023) / 1024;   // 98 (<256, fits single-block scan)

    init_counts<<<256, 256, 0, stream>>>(counts, cursor, n);
    count_kernel<<<1024, 256, 0, stream>>>(dst, counts, e);
    dinv_kernel<<<(n + 255) / 256, 256, 0, stream>>>(counts, dinv, n);
    scan_partial<<<nb_scan, 256, 0, stream>>>(counts, offs, bsums, n);
    scan_bsums<<<1, 256, 0, stream>>>(bsums, nb_scan);
    scan_add<<<512, 256, 0, stream>>>(offs, bsums, n, e);
    fill_kernel<<<1024, 256, 0, stream>>>(src, dst, offs, cursor, dinv, csr_src, csr_norm, e);

    // layer 1: xw1 = x@W1 ; h = relu(agg(xw1) + b1)
    matmul_kernel<32, 128><<<(n + 31) / 32, 256, 0, stream>>>(x, W1, xw1, n);
    agg128_kernel<<<n, 128, 0, stream>>>(xw1, offs, csr_src, csr_norm, dinv, b1, h, n, 1);

    // layer 2: xw2 = h@W2 ; out = agg(xw2) + b2
    matmul_kernel<64, 32><<<(n + 63) / 64, 128, 0, stream>>>(h, W2, xw2, n);
    agg32_kernel<<<(n + 3) / 4, 128, 0, stream>>>(xw2, offs, csr_src, csr_norm, dinv, b2, out, n);
}

// Round 2
// 416.063 us; speedup vs baseline: 1.2532x; 1.2532x over previous
//
#include <hip/hip_runtime.h>

// ---------------------------------------------------------------------------
// 2-layer GCN: z = A_hat (relu(A_hat (X W1) + b1)) W2 + b2
// A_hat = D^-1/2 (A + I) D^-1/2, deg on dst incl. self-loops.
// CSR-by-dst built once; transform-then-aggregate for both layers.
// Aggregation v2: wave-per-node, float4 gathers, multi-edge MLP, packed
// (src,norm) int2 edge records. No atomics in the hot path.
// ---------------------------------------------------------------------------

#define KDIM 128

__global__ void init_counts(int* counts, int* cursor, int n) {
    int i = blockIdx.x * blockDim.x + threadIdx.x;
    int stride = gridDim.x * blockDim.x;
    for (; i < n; i += stride) { counts[i] = 0; cursor[i] = 0; }
}

__global__ void count_kernel(const int* __restrict__ dst, int* __restrict__ counts, int e) {
    int i = blockIdx.x * blockDim.x + threadIdx.x;
    int stride = gridDim.x * blockDim.x;
    for (; i < e; i += stride) atomicAdd(&counts[dst[i]], 1);
}

__global__ void dinv_kernel(const int* __restrict__ counts, float* __restrict__ dinv, int n) {
    int i = blockIdx.x * blockDim.x + threadIdx.x;
    int stride = gridDim.x * blockDim.x;
    for (; i < n; i += stride) dinv[i] = rsqrtf((float)(counts[i] + 1));  // +1 self loop
}

// --- 3-kernel exclusive scan over counts -> offsets -------------------------
__global__ void scan_partial(const int* __restrict__ counts, int* __restrict__ local,
                             int* __restrict__ bsums, int n) {
    __shared__ int ld[1024];
    __shared__ int ts[256];
    const int t = threadIdx.x;
    const int base = blockIdx.x * 1024;
    for (int j = t; j < 1024; j += 256) ld[j] = (base + j < n) ? counts[base + j] : 0;
    __syncthreads();
    int a0 = ld[4*t], a1 = ld[4*t+1], a2 = ld[4*t+2], a3 = ld[4*t+3];
    int sum = a0 + a1 + a2 + a3;
    ts[t] = sum;
    for (int off = 1; off < 256; off <<= 1) {
        __syncthreads();
        int v = (t >= off) ? ts[t - off] : 0;
        __syncthreads();
        ts[t] += v;
    }
    __syncthreads();
    int excl = ts[t] - sum;
    if (base + 4*t + 0 < n) local[base + 4*t + 0] = excl;
    if (base + 4*t + 1 < n) local[base + 4*t + 1] = excl + a0;
    if (base + 4*t + 2 < n) local[base + 4*t + 2] = excl + a0 + a1;
    if (base + 4*t + 3 < n) local[base + 4*t + 3] = excl + a0 + a1 + a2;
    if (t == 255) bsums[blockIdx.x] = ts[255];
}

__global__ void scan_bsums(int* __restrict__ bsums, int nb) {
    __shared__ int ts[256];
    const int t = threadIdx.x;
    int v = (t < nb) ? bsums[t] : 0;
    ts[t] = v;
    for (int off = 1; off < 256; off <<= 1) {
        __syncthreads();
        int u = (t >= off) ? ts[t - off] : 0;
        __syncthreads();
        ts[t] += u;
    }
    __syncthreads();
    if (t < nb) bsums[t] = ts[t] - v;
}

__global__ void scan_add(int* __restrict__ offs, const int* __restrict__ bsums, int n, int e_total) {
    int i = blockIdx.x * blockDim.x + threadIdx.x;
    int stride = gridDim.x * blockDim.x;
    for (; i < n; i += stride) offs[i] += bsums[i >> 10];
    if (blockIdx.x == 0 && threadIdx.x == 0) offs[n] = e_total;
}

__global__ void fill_kernel(const int* __restrict__ src, const int* __restrict__ dst,
                            const int* __restrict__ offs, int* __restrict__ cursor,
                            const float* __restrict__ dinv,
                            int2* __restrict__ csr, int e) {
    int i = blockIdx.x * blockDim.x + threadIdx.x;
    int stride = gridDim.x * blockDim.x;
    for (; i < e; i += stride) {
        int s = src[i], d = dst[i];
        int pos = offs[d] + atomicAdd(&cursor[d], 1);
        int2 rec;
        rec.x = s;
        rec.y = __float_as_int(dinv[s] * dinv[d]);
        csr[pos] = rec;
    }
}

// --- dense matmul: out[n x DOUT] = x[n x 128] @ W[128 x DOUT] ---------------
template<int ROWS, int DOUT>
__global__ __launch_bounds__((ROWS/4)*(DOUT/4))
void matmul_kernel(const float* __restrict__ x, const float* __restrict__ W,
                   float* __restrict__ out, int n) {
    constexpr int K = KDIM;
    constexpr int TPB = (ROWS/4) * (DOUT/4);
    __shared__ float xs[ROWS][K];
    __shared__ float ws[K][DOUT];
    const int tid = threadIdx.x;
    const int row0 = blockIdx.x * ROWS;

    for (int idx = tid; idx < K*DOUT/4; idx += TPB)
        ((float4*)ws)[idx] = ((const float4*)W)[idx];
    for (int idx = tid; idx < ROWS*K/4; idx += TPB) {
        int r = idx / (K/4);
        int row = row0 + r;
        float4 v = (row < n) ? ((const float4*)x)[(size_t)row*(K/4) + (idx % (K/4))]
                             : make_float4(0.f, 0.f, 0.f, 0.f);
        ((float4*)xs)[idx] = v;
    }
    __syncthreads();

    const int tc = tid % (DOUT/4);
    const int tr = tid / (DOUT/4);
    float acc[4][4] = {};
    #pragma unroll 4
    for (int k = 0; k < K; k += 4) {
        float xa[4][4], wb[4][4];
        #pragma unroll
        for (int r = 0; r < 4; ++r) {
            float4 v = *(const float4*)&xs[tr*4 + r][k];
            xa[r][0] = v.x; xa[r][1] = v.y; xa[r][2] = v.z; xa[r][3] = v.w;
        }
        #pragma unroll
        for (int kk = 0; kk < 4; ++kk) {
            float4 v = *(const float4*)&ws[k + kk][tc*4];
            wb[kk][0] = v.x; wb[kk][1] = v.y; wb[kk][2] = v.z; wb[kk][3] = v.w;
        }
        #pragma unroll
        for (int r = 0; r < 4; ++r)
            #pragma unroll
            for (int kk = 0; kk < 4; ++kk)
                #pragma unroll
                for (int c = 0; c < 4; ++c)
                    acc[r][c] += xa[r][kk] * wb[kk][c];
    }
    #pragma unroll
    for (int r = 0; r < 4; ++r) {
        int row = row0 + tr*4 + r;
        if (row < n) {
            float4 v = make_float4(acc[r][0], acc[r][1], acc[r][2], acc[r][3]);
            *(float4*)&out[(size_t)row*DOUT + tc*4] = v;
        }
    }
}

// --- aggregation, D=128: one wave per node ----------------------------------
// lane halves (0-31 / 32-63) process alternate edges; each lane gathers a
// float4 (wave reads 1KB/instr across 2 edge rows); unroll x2 -> 4 edges in
// flight per wave. Shuffle-combine halves at the end.
__global__ __launch_bounds__(256)
void agg128_kernel(const float* __restrict__ xw, const int* __restrict__ offs,
                   const int2* __restrict__ csr, const float* __restrict__ dinv,
                   const float* __restrict__ bias, float* __restrict__ out,
                   int n, int do_relu) {
    const int w = threadIdx.x >> 6;
    const int i = blockIdx.x * 4 + w;
    if (i >= n) return;
    const int lane = threadIdx.x & 63;
    const int half = lane >> 5;
    const int q = lane & 31;

    float4 acc = make_float4(0.f, 0.f, 0.f, 0.f);
    const int e0 = offs[i], e1 = offs[i + 1];
    int e = e0 + half;
    for (; e + 2 < e1; e += 4) {
        int2 p0 = csr[e];
        int2 p1 = csr[e + 2];
        const float4 v0 = *(const float4*)&xw[(size_t)p0.x * 128 + q * 4];
        const float4 v1 = *(const float4*)&xw[(size_t)p1.x * 128 + q * 4];
        const float n0 = __int_as_float(p0.y);
        const float n1 = __int_as_float(p1.y);
        acc.x += v0.x * n0; acc.y += v0.y * n0; acc.z += v0.z * n0; acc.w += v0.w * n0;
        acc.x += v1.x * n1; acc.y += v1.y * n1; acc.z += v1.z * n1; acc.w += v1.w * n1;
    }
    if (e < e1) {
        int2 p = csr[e];
        const float4 v = *(const float4*)&xw[(size_t)p.x * 128 + q * 4];
        const float nr = __int_as_float(p.y);
        acc.x += v.x * nr; acc.y += v.y * nr; acc.z += v.z * nr; acc.w += v.w * nr;
    }
    // combine the two halves (lane ^ 32 holds same dims, other edge parity)
    acc.x += __shfl_xor(acc.x, 32, 64);
    acc.y += __shfl_xor(acc.y, 32, 64);
    acc.z += __shfl_xor(acc.z, 32, 64);
    acc.w += __shfl_xor(acc.w, 32, 64);

    if (half == 0) {
        const float di = dinv[i];
        const float s = di * di;
        const float4 sv = *(const float4*)&xw[(size_t)i * 128 + q * 4];
        const float4 b  = *(const float4*)&bias[q * 4];
        float4 r;
        r.x = acc.x + sv.x * s + b.x;
        r.y = acc.y + sv.y * s + b.y;
        r.z = acc.z + sv.z * s + b.z;
        r.w = acc.w + sv.w * s + b.w;
        if (do_relu) {
            r.x = fmaxf(r.x, 0.f); r.y = fmaxf(r.y, 0.f);
            r.z = fmaxf(r.z, 0.f); r.w = fmaxf(r.w, 0.f);
        }
        *(float4*)&out[(size_t)i * 128 + q * 4] = r;
    }
}

// --- aggregation, D=32: one wave per node, 8 edges in parallel --------------
// lane l: edge-group g = l>>3, dim-quad q = l&7. Unroll x2 -> 16 edges in
// flight. Reduce over g via shfl_xor(8,16,32); group 0 writes the row.
__global__ __launch_bounds__(256)
void agg32_kernel(const float* __restrict__ xw, const int* __restrict__ offs,
                  const int2* __restrict__ csr, const float* __restrict__ dinv,
                  const float* __restrict__ bias, float* __restrict__ out, int n) {
    const int w = threadIdx.x >> 6;
    const int i = blockIdx.x * 4 + w;
    if (i >= n) return;
    const int lane = threadIdx.x & 63;
    const int g = lane >> 3;
    const int q = lane & 7;

    float4 acc = make_float4(0.f, 0.f, 0.f, 0.f);
    const int e0 = offs[i], e1 = offs[i + 1];
    int e = e0 + g;
    for (; e + 8 < e1; e += 16) {
        int2 p0 = csr[e];
        int2 p1 = csr[e + 8];
        const float4 v0 = *(const float4*)&xw[(size_t)p0.x * 32 + q * 4];
        const float4 v1 = *(const float4*)&xw[(size_t)p1.x * 32 + q * 4];
        const float n0 = __int_as_float(p0.y);
        const float n1 = __int_as_float(p1.y);
        acc.x += v0.x * n0; acc.y += v0.y * n0; acc.z += v0.z * n0; acc.w += v0.w * n0;
        acc.x += v1.x * n1; acc.y += v1.y * n1; acc.z += v1.z * n1; acc.w += v1.w * n1;
    }
    if (e < e1) {
        int2 p = csr[e];
        const float4 v = *(const float4*)&xw[(size_t)p.x * 32 + q * 4];
        const float nr = __int_as_float(p.y);
        acc.x += v.x * nr; acc.y += v.y * nr; acc.z += v.z * nr; acc.w += v.w * nr;
    }
    #pragma unroll
    for (int m = 8; m <= 32; m <<= 1) {
        acc.x += __shfl_xor(acc.x, m, 64);
        acc.y += __shfl_xor(acc.y, m, 64);
        acc.z += __shfl_xor(acc.z, m, 64);
        acc.w += __shfl_xor(acc.w, m, 64);
    }

    if (g == 0) {
        const float di = dinv[i];
        const float s = di * di;
        const float4 sv = *(const float4*)&xw[(size_t)i * 32 + q * 4];
        const float4 b  = *(const float4*)&bias[q * 4];
        float4 r;
        r.x = acc.x + sv.x * s + b.x;
        r.y = acc.y + sv.y * s + b.y;
        r.z = acc.z + sv.z * s + b.z;
        r.w = acc.w + sv.w * s + b.w;
        *(float4*)&out[(size_t)i * 32 + q * 4] = r;
    }
}

extern "C" void kernel_launch(void* const* d_in, const int* in_sizes, int n_in,
                              void* d_out, int out_size, void* d_ws, size_t ws_size,
                              hipStream_t stream) {
    const int n = in_sizes[0] / KDIM;      // 100000
    const int e = in_sizes[1] / 2;         // 1600000

    const float* x  = (const float*)d_in[0];
    const int*   ei = (const int*)d_in[1];
    const int*   src = ei;
    const int*   dst = ei + e;
    const float* W1 = (const float*)d_in[2];
    const float* b1 = (const float*)d_in[3];
    const float* W2 = (const float*)d_in[4];
    const float* b2 = (const float*)d_in[5];
    float* out = (float*)d_out;

    // workspace carve (256B aligned)
    char* p = (char*)d_ws;
    auto alloc = [&](size_t bytes) { char* q = p; p += (bytes + 255) & ~(size_t)255; return q; };
    float* dinv     = (float*)alloc((size_t)n * 4);
    int*   counts   = (int*)  alloc((size_t)n * 4);
    int*   cursor   = (int*)  alloc((size_t)n * 4);
    int*   offs     = (int*)  alloc((size_t)(n + 1) * 4);
    int*   bsums    = (int*)  alloc(1024 * 4);
    int2*  csr      = (int2*) alloc((size_t)e * 8);
    float* xw1      = (float*)alloc((size_t)n * 128 * 4);
    float* h        = (float*)alloc((size_t)n * 128 * 4);
    float* xw2      = (float*)alloc((size_t)n * 32 * 4);

    const int nb_scan = (n + 1023) / 1024;   // 98 (<256, fits single-block scan)

    init_counts<<<256, 256, 0, stream>>>(counts, cursor, n);
    count_kernel<<<1024, 256, 0, stream>>>(dst, counts, e);
    dinv_kernel<<<(n + 255) / 256, 256, 0, stream>>>(counts, dinv, n);
    scan_partial<<<nb_scan, 256, 0, stream>>>(counts, offs, bsums, n);
    scan_bsums<<<1, 256, 0, stream>>>(bsums, nb_scan);
    scan_add<<<512, 256, 0, stream>>>(offs, bsums, n, e);
    fill_kernel<<<1024, 256, 0, stream>>>(src, dst, offs, cursor, dinv, csr, e);

    // layer 1: xw1 = x@W1 ; h = relu(agg(xw1) + b1)
    matmul_kernel<32, 128><<<(n + 31) / 32, 256, 0, stream>>>(x, W1, xw1, n);
    agg128_kernel<<<(n + 3) / 4, 256, 0, stream>>>(xw1, offs, csr, dinv, b1, h, n, 1);

    // layer 2: xw2 = h@W2 ; out = agg(xw2) + b2
    matmul_kernel<64, 32><<<(n + 63) / 64, 128, 0, stream>>>(h, W2, xw2, n);
    agg32_kernel<<<(n + 3) / 4, 256, 0, stream>>>(xw2, offs, csr, dinv, b2, out, n);
}

// Round 3
// 382.865 us; speedup vs baseline: 1.3618x; 1.0867x over previous
//
#include <hip/hip_runtime.h>

// ---------------------------------------------------------------------------
// 2-layer GCN: z = A_hat (relu(A_hat (X W1) + b1)) W2 + b2
// CSR-by-dst built once; transform-then-aggregate for both layers.
// R3: xw1 stored as bf16 (halves the dominant gather traffic; 4 edges per
// wave-instr), matmul1 rebuilt as 64x128 tile / 8x8 acc per thread.
// ---------------------------------------------------------------------------

#define KDIM 128

typedef unsigned int uint;
typedef unsigned short ushort;

__device__ inline ushort f2bf(float f) {              // RNE f32 -> bf16
    uint u = __float_as_uint(f);
    return (ushort)((u + 0x7fffu + ((u >> 16) & 1u)) >> 16);
}

__global__ void init_counts(int* counts, int* cursor, int n) {
    int i = blockIdx.x * blockDim.x + threadIdx.x;
    int stride = gridDim.x * blockDim.x;
    for (; i < n; i += stride) { counts[i] = 0; cursor[i] = 0; }
}

__global__ void count_kernel(const int* __restrict__ dst, int* __restrict__ counts, int e) {
    int i = blockIdx.x * blockDim.x + threadIdx.x;
    int stride = gridDim.x * blockDim.x;
    for (; i < e; i += stride) atomicAdd(&counts[dst[i]], 1);
}

__global__ void dinv_kernel(const int* __restrict__ counts, float* __restrict__ dinv, int n) {
    int i = blockIdx.x * blockDim.x + threadIdx.x;
    int stride = gridDim.x * blockDim.x;
    for (; i < n; i += stride) dinv[i] = rsqrtf((float)(counts[i] + 1));
}

// --- 3-kernel exclusive scan over counts -> offsets -------------------------
__global__ void scan_partial(const int* __restrict__ counts, int* __restrict__ local,
                             int* __restrict__ bsums, int n) {
    __shared__ int ld[1024];
    __shared__ int ts[256];
    const int t = threadIdx.x;
    const int base = blockIdx.x * 1024;
    for (int j = t; j < 1024; j += 256) ld[j] = (base + j < n) ? counts[base + j] : 0;
    __syncthreads();
    int a0 = ld[4*t], a1 = ld[4*t+1], a2 = ld[4*t+2], a3 = ld[4*t+3];
    int sum = a0 + a1 + a2 + a3;
    ts[t] = sum;
    for (int off = 1; off < 256; off <<= 1) {
        __syncthreads();
        int v = (t >= off) ? ts[t - off] : 0;
        __syncthreads();
        ts[t] += v;
    }
    __syncthreads();
    int excl = ts[t] - sum;
    if (base + 4*t + 0 < n) local[base + 4*t + 0] = excl;
    if (base + 4*t + 1 < n) local[base + 4*t + 1] = excl + a0;
    if (base + 4*t + 2 < n) local[base + 4*t + 2] = excl + a0 + a1;
    if (base + 4*t + 3 < n) local[base + 4*t + 3] = excl + a0 + a1 + a2;
    if (t == 255) bsums[blockIdx.x] = ts[255];
}

__global__ void scan_bsums(int* __restrict__ bsums, int nb) {
    __shared__ int ts[256];
    const int t = threadIdx.x;
    int v = (t < nb) ? bsums[t] : 0;
    ts[t] = v;
    for (int off = 1; off < 256; off <<= 1) {
        __syncthreads();
        int u = (t >= off) ? ts[t - off] : 0;
        __syncthreads();
        ts[t] += u;
    }
    __syncthreads();
    if (t < nb) bsums[t] = ts[t] - v;
}

__global__ void scan_add(int* __restrict__ offs, const int* __restrict__ bsums, int n, int e_total) {
    int i = blockIdx.x * blockDim.x + threadIdx.x;
    int stride = gridDim.x * blockDim.x;
    for (; i < n; i += stride) offs[i] += bsums[i >> 10];
    if (blockIdx.x == 0 && threadIdx.x == 0) offs[n] = e_total;
}

__global__ void fill_kernel(const int* __restrict__ src, const int* __restrict__ dst,
                            const int* __restrict__ offs, int* __restrict__ cursor,
                            const float* __restrict__ dinv,
                            int2* __restrict__ csr, int e) {
    int i = blockIdx.x * blockDim.x + threadIdx.x;
    int stride = gridDim.x * blockDim.x;
    for (; i < e; i += stride) {
        int s = src[i], d = dst[i];
        int pos = offs[d] + atomicAdd(&cursor[d], 1);
        int2 rec;
        rec.x = s;
        rec.y = __float_as_int(dinv[s] * dinv[d]);
        csr[pos] = rec;
    }
}

// --- matmul1: outb[n x 128] (bf16) = x[n x 128] @ W[128 x 128] --------------
// 128 thr/block, 64x128 tile, 8x8 acc/thread, k-chunked (32) LDS.
__global__ __launch_bounds__(128)
void matmul1_kernel(const float* __restrict__ x, const float* __restrict__ W,
                    ushort* __restrict__ outb, int n) {
    __shared__ float xs[32][68];   // [kk][row] transposed, stride 68 keeps 16B align
    __shared__ float ws[32][128];  // [kk][col]
    const int tid = threadIdx.x;
    const int row0 = blockIdx.x * 64;
    const int tr = tid >> 4;       // 0..7 -> rows tr*8..+7
    const int tcc = tid & 15;      // cols tcc*8..+7
    float acc[8][8] = {};
    for (int c = 0; c < 4; ++c) {
        const int k0 = c * 32;
        #pragma unroll
        for (int j = 0; j < 8; ++j) {
            int idx = tid + j * 128;            // float4 idx into W chunk (1024)
            int kk = idx >> 5;
            int c4 = idx & 31;
            *(float4*)&ws[kk][c4 * 4] = *(const float4*)&W[(size_t)(k0 + kk) * 128 + c4 * 4];
        }
        #pragma unroll
        for (int j = 0; j < 4; ++j) {
            int idx = tid + j * 128;            // float4 idx into x chunk (512)
            int r = idx >> 3;
            int kq = idx & 7;
            int row = row0 + r;
            float4 v = (row < n) ? *(const float4*)&x[(size_t)row * 128 + k0 + kq * 4]
                                 : make_float4(0.f, 0.f, 0.f, 0.f);
            xs[kq * 4 + 0][r] = v.x;
            xs[kq * 4 + 1][r] = v.y;
            xs[kq * 4 + 2][r] = v.z;
            xs[kq * 4 + 3][r] = v.w;
        }
        __syncthreads();
        #pragma unroll
        for (int kk = 0; kk < 32; ++kk) {
            float4 a0 = *(const float4*)&xs[kk][tr * 8];
            float4 a1 = *(const float4*)&xs[kk][tr * 8 + 4];
            float4 b0 = *(const float4*)&ws[kk][tcc * 8];
            float4 b1 = *(const float4*)&ws[kk][tcc * 8 + 4];
            float av[8] = {a0.x, a0.y, a0.z, a0.w, a1.x, a1.y, a1.z, a1.w};
            float bv[8] = {b0.x, b0.y, b0.z, b0.w, b1.x, b1.y, b1.z, b1.w};
            #pragma unroll
            for (int r = 0; r < 8; ++r)
                #pragma unroll
                for (int cc = 0; cc < 8; ++cc)
                    acc[r][cc] += av[r] * bv[cc];
        }
        __syncthreads();
    }
    #pragma unroll
    for (int r = 0; r < 8; ++r) {
        int row = row0 + tr * 8 + r;
        if (row < n) {
            ushort us[8];
            #pragma unroll
            for (int cc = 0; cc < 8; ++cc) us[cc] = f2bf(acc[r][cc]);
            *(uint4*)&outb[(size_t)row * 128 + tcc * 8] = *(const uint4*)us;
        }
    }
}

// --- generic small matmul (layer 2): out[n x DOUT] = x[n x 128] @ W ---------
template<int ROWS, int DOUT>
__global__ __launch_bounds__((ROWS/4)*(DOUT/4))
void matmul_kernel(const float* __restrict__ x, const float* __restrict__ W,
                   float* __restrict__ out, int n) {
    constexpr int K = KDIM;
    constexpr int TPB = (ROWS/4) * (DOUT/4);
    __shared__ float xs[ROWS][K];
    __shared__ float ws[K][DOUT];
    const int tid = threadIdx.x;
    const int row0 = blockIdx.x * ROWS;

    for (int idx = tid; idx < K*DOUT/4; idx += TPB)
        ((float4*)ws)[idx] = ((const float4*)W)[idx];
    for (int idx = tid; idx < ROWS*K/4; idx += TPB) {
        int r = idx / (K/4);
        int row = row0 + r;
        float4 v = (row < n) ? ((const float4*)x)[(size_t)row*(K/4) + (idx % (K/4))]
                             : make_float4(0.f, 0.f, 0.f, 0.f);
        ((float4*)xs)[idx] = v;
    }
    __syncthreads();

    const int tc = tid % (DOUT/4);
    const int tr = tid / (DOUT/4);
    float acc[4][4] = {};
    #pragma unroll 4
    for (int k = 0; k < K; k += 4) {
        float xa[4][4], wb[4][4];
        #pragma unroll
        for (int r = 0; r < 4; ++r) {
            float4 v = *(const float4*)&xs[tr*4 + r][k];
            xa[r][0] = v.x; xa[r][1] = v.y; xa[r][2] = v.z; xa[r][3] = v.w;
        }
        #pragma unroll
        for (int kk = 0; kk < 4; ++kk) {
            float4 v = *(const float4*)&ws[k + kk][tc*4];
            wb[kk][0] = v.x; wb[kk][1] = v.y; wb[kk][2] = v.z; wb[kk][3] = v.w;
        }
        #pragma unroll
        for (int r = 0; r < 4; ++r)
            #pragma unroll
            for (int kk = 0; kk < 4; ++kk)
                #pragma unroll
                for (int c = 0; c < 4; ++c)
                    acc[r][c] += xa[r][kk] * wb[kk][c];
    }
    #pragma unroll
    for (int r = 0; r < 4; ++r) {
        int row = row0 + tr*4 + r;
        if (row < n) {
            float4 v = make_float4(acc[r][0], acc[r][1], acc[r][2], acc[r][3]);
            *(float4*)&out[(size_t)row*DOUT + tc*4] = v;
        }
    }
}

// --- aggregation, D=128 over bf16 rows: one wave per node -------------------
// lane: g = lane>>4 (edge group 0..3), q = lane&15 (dim octet). Row = 256B,
// so one wave-instr gathers 4 edge rows; unroll x2 -> 8 edges in flight.
__device__ inline void bf2_fma(uint u, float nr, float& a0, float& a1) {
    a0 += __uint_as_float(u << 16) * nr;
    a1 += __uint_as_float(u & 0xffff0000u) * nr;
}

__global__ __launch_bounds__(256)
void agg128_kernel(const ushort* __restrict__ xwb, const int* __restrict__ offs,
                   const int2* __restrict__ csr, const float* __restrict__ dinv,
                   const float* __restrict__ bias, float* __restrict__ out,
                   int n, int do_relu) {
    const int w = threadIdx.x >> 6;
    const int i = blockIdx.x * 4 + w;
    if (i >= n) return;
    const int lane = threadIdx.x & 63;
    const int g = lane >> 4;
    const int q = lane & 15;

    float acc[8] = {};
    const int e0 = offs[i], e1 = offs[i + 1];
    int e = e0 + g;
    for (; e + 4 < e1; e += 8) {
        int2 p0 = csr[e];
        int2 p1 = csr[e + 4];
        uint4 u0 = *(const uint4*)&xwb[(size_t)p0.x * 128 + q * 8];
        uint4 u1 = *(const uint4*)&xwb[(size_t)p1.x * 128 + q * 8];
        float n0 = __int_as_float(p0.y);
        float n1 = __int_as_float(p1.y);
        bf2_fma(u0.x, n0, acc[0], acc[1]);
        bf2_fma(u0.y, n0, acc[2], acc[3]);
        bf2_fma(u0.z, n0, acc[4], acc[5]);
        bf2_fma(u0.w, n0, acc[6], acc[7]);
        bf2_fma(u1.x, n1, acc[0], acc[1]);
        bf2_fma(u1.y, n1, acc[2], acc[3]);
        bf2_fma(u1.z, n1, acc[4], acc[5]);
        bf2_fma(u1.w, n1, acc[6], acc[7]);
    }
    if (e < e1) {
        int2 p = csr[e];
        uint4 u = *(const uint4*)&xwb[(size_t)p.x * 128 + q * 8];
        float nr = __int_as_float(p.y);
        bf2_fma(u.x, nr, acc[0], acc[1]);
        bf2_fma(u.y, nr, acc[2], acc[3]);
        bf2_fma(u.z, nr, acc[4], acc[5]);
        bf2_fma(u.w, nr, acc[6], acc[7]);
    }
    #pragma unroll
    for (int j = 0; j < 8; ++j) {
        acc[j] += __shfl_xor(acc[j], 16, 64);
        acc[j] += __shfl_xor(acc[j], 32, 64);
    }

    if (g == 0) {
        const float di = dinv[i];
        const float s = di * di;
        uint4 su = *(const uint4*)&xwb[(size_t)i * 128 + q * 8];
        bf2_fma(su.x, s, acc[0], acc[1]);
        bf2_fma(su.y, s, acc[2], acc[3]);
        bf2_fma(su.z, s, acc[4], acc[5]);
        bf2_fma(su.w, s, acc[6], acc[7]);
        const float4 b0 = *(const float4*)&bias[q * 8];
        const float4 b1 = *(const float4*)&bias[q * 8 + 4];
        float4 r0, r1;
        r0.x = acc[0] + b0.x; r0.y = acc[1] + b0.y; r0.z = acc[2] + b0.z; r0.w = acc[3] + b0.w;
        r1.x = acc[4] + b1.x; r1.y = acc[5] + b1.y; r1.z = acc[6] + b1.z; r1.w = acc[7] + b1.w;
        if (do_relu) {
            r0.x = fmaxf(r0.x, 0.f); r0.y = fmaxf(r0.y, 0.f);
            r0.z = fmaxf(r0.z, 0.f); r0.w = fmaxf(r0.w, 0.f);
            r1.x = fmaxf(r1.x, 0.f); r1.y = fmaxf(r1.y, 0.f);
            r1.z = fmaxf(r1.z, 0.f); r1.w = fmaxf(r1.w, 0.f);
        }
        *(float4*)&out[(size_t)i * 128 + q * 8] = r0;
        *(float4*)&out[(size_t)i * 128 + q * 8 + 4] = r1;
    }
}

// --- aggregation, D=32 (f32): one wave per node, 8 edges in parallel --------
__global__ __launch_bounds__(256)
void agg32_kernel(const float* __restrict__ xw, const int* __restrict__ offs,
                  const int2* __restrict__ csr, const float* __restrict__ dinv,
                  const float* __restrict__ bias, float* __restrict__ out, int n) {
    const int w = threadIdx.x >> 6;
    const int i = blockIdx.x * 4 + w;
    if (i >= n) return;
    const int lane = threadIdx.x & 63;
    const int g = lane >> 3;
    const int q = lane & 7;

    float4 acc = make_float4(0.f, 0.f, 0.f, 0.f);
    const int e0 = offs[i], e1 = offs[i + 1];
    int e = e0 + g;
    for (; e + 8 < e1; e += 16) {
        int2 p0 = csr[e];
        int2 p1 = csr[e + 8];
        const float4 v0 = *(const float4*)&xw[(size_t)p0.x * 32 + q * 4];
        const float4 v1 = *(const float4*)&xw[(size_t)p1.x * 32 + q * 4];
        const float n0 = __int_as_float(p0.y);
        const float n1 = __int_as_float(p1.y);
        acc.x += v0.x * n0; acc.y += v0.y * n0; acc.z += v0.z * n0; acc.w += v0.w * n0;
        acc.x += v1.x * n1; acc.y += v1.y * n1; acc.z += v1.z * n1; acc.w += v1.w * n1;
    }
    if (e < e1) {
        int2 p = csr[e];
        const float4 v = *(const float4*)&xw[(size_t)p.x * 32 + q * 4];
        const float nr = __int_as_float(p.y);
        acc.x += v.x * nr; acc.y += v.y * nr; acc.z += v.z * nr; acc.w += v.w * nr;
    }
    #pragma unroll
    for (int m = 8; m <= 32; m <<= 1) {
        acc.x += __shfl_xor(acc.x, m, 64);
        acc.y += __shfl_xor(acc.y, m, 64);
        acc.z += __shfl_xor(acc.z, m, 64);
        acc.w += __shfl_xor(acc.w, m, 64);
    }

    if (g == 0) {
        const float di = dinv[i];
        const float s = di * di;
        const float4 sv = *(const float4*)&xw[(size_t)i * 32 + q * 4];
        const float4 b  = *(const float4*)&bias[q * 4];
        float4 r;
        r.x = acc.x + sv.x * s + b.x;
        r.y = acc.y + sv.y * s + b.y;
        r.z = acc.z + sv.z * s + b.z;
        r.w = acc.w + sv.w * s + b.w;
        *(float4*)&out[(size_t)i * 32 + q * 4] = r;
    }
}

extern "C" void kernel_launch(void* const* d_in, const int* in_sizes, int n_in,
                              void* d_out, int out_size, void* d_ws, size_t ws_size,
                              hipStream_t stream) {
    const int n = in_sizes[0] / KDIM;      // 100000
    const int e = in_sizes[1] / 2;         // 1600000

    const float* x  = (const float*)d_in[0];
    const int*   ei = (const int*)d_in[1];
    const int*   src = ei;
    const int*   dst = ei + e;
    const float* W1 = (const float*)d_in[2];
    const float* b1 = (const float*)d_in[3];
    const float* W2 = (const float*)d_in[4];
    const float* b2 = (const float*)d_in[5];
    float* out = (float*)d_out;

    // workspace carve (256B aligned)
    char* p = (char*)d_ws;
    auto alloc = [&](size_t bytes) { char* q = p; p += (bytes + 255) & ~(size_t)255; return q; };
    float*  dinv   = (float*)alloc((size_t)n * 4);
    int*    counts = (int*)  alloc((size_t)n * 4);
    int*    cursor = (int*)  alloc((size_t)n * 4);
    int*    offs   = (int*)  alloc((size_t)(n + 1) * 4);
    int*    bsums  = (int*)  alloc(1024 * 4);
    int2*   csr    = (int2*) alloc((size_t)e * 8);
    ushort* xw1b   = (ushort*)alloc((size_t)n * 128 * 2);
    float*  h      = (float*)alloc((size_t)n * 128 * 4);
    float*  xw2    = (float*)alloc((size_t)n * 32 * 4);

    const int nb_scan = (n + 1023) / 1024;

    init_counts<<<256, 256, 0, stream>>>(counts, cursor, n);
    count_kernel<<<1024, 256, 0, stream>>>(dst, counts, e);
    dinv_kernel<<<(n + 255) / 256, 256, 0, stream>>>(counts, dinv, n);
    scan_partial<<<nb_scan, 256, 0, stream>>>(counts, offs, bsums, n);
    scan_bsums<<<1, 256, 0, stream>>>(bsums, nb_scan);
    scan_add<<<512, 256, 0, stream>>>(offs, bsums, n, e);
    fill_kernel<<<1024, 256, 0, stream>>>(src, dst, offs, cursor, dinv, csr, e);

    // layer 1: xw1b = bf16(x@W1) ; h = relu(agg(xw1b) + b1)
    matmul1_kernel<<<(n + 63) / 64, 128, 0, stream>>>(x, W1, xw1b, n);
    agg128_kernel<<<(n + 3) / 4, 256, 0, stream>>>(xw1b, offs, csr, dinv, b1, h, n, 1);

    // layer 2: xw2 = h@W2 ; out = agg(xw2) + b2
    matmul_kernel<64, 32><<<(n + 63) / 64, 128, 0, stream>>>(h, W2, xw2, n);
    agg32_kernel<<<(n + 3) / 4, 256, 0, stream>>>(xw2, offs, csr, dinv, b2, out, n);
}

// Round 4
// 318.000 us; speedup vs baseline: 1.6396x; 1.2040x over previous
//
#include <hip/hip_runtime.h>

// ---------------------------------------------------------------------------
// 2-layer GCN: z = A_hat (relu(A_hat (X W1) + b1)) W2 + b2
// CSR-by-dst built once; transform-then-aggregate for both layers.
// R4: matmul1 -> bf16 MFMA (16x16x32), A-frags straight from f32 x (in-reg
// convert), W1 pre-packed to B-fragment order + LDS. Rest unchanged.
// ---------------------------------------------------------------------------

#define KDIM 128

typedef unsigned int uint;
typedef unsigned short ushort;
typedef __attribute__((ext_vector_type(8))) short bf16x8;
typedef __attribute__((ext_vector_type(4))) float f32x4;

__device__ inline ushort f2bf(float f) {              // RNE f32 -> bf16
    uint u = __float_as_uint(f);
    return (ushort)((u + 0x7fffu + ((u >> 16) & 1u)) >> 16);
}

__global__ void init_counts(int* counts, int* cursor, int n) {
    int i = blockIdx.x * blockDim.x + threadIdx.x;
    int stride = gridDim.x * blockDim.x;
    for (; i < n; i += stride) { counts[i] = 0; cursor[i] = 0; }
}

__global__ void count_kernel(const int* __restrict__ dst, int* __restrict__ counts, int e) {
    int i = blockIdx.x * blockDim.x + threadIdx.x;
    int stride = gridDim.x * blockDim.x;
    for (; i < e; i += stride) atomicAdd(&counts[dst[i]], 1);
}

__global__ void dinv_kernel(const int* __restrict__ counts, float* __restrict__ dinv, int n) {
    int i = blockIdx.x * blockDim.x + threadIdx.x;
    int stride = gridDim.x * blockDim.x;
    for (; i < n; i += stride) dinv[i] = rsqrtf((float)(counts[i] + 1));
}

// --- 3-kernel exclusive scan over counts -> offsets -------------------------
__global__ void scan_partial(const int* __restrict__ counts, int* __restrict__ local,
                             int* __restrict__ bsums, int n) {
    __shared__ int ld[1024];
    __shared__ int ts[256];
    const int t = threadIdx.x;
    const int base = blockIdx.x * 1024;
    for (int j = t; j < 1024; j += 256) ld[j] = (base + j < n) ? counts[base + j] : 0;
    __syncthreads();
    int a0 = ld[4*t], a1 = ld[4*t+1], a2 = ld[4*t+2], a3 = ld[4*t+3];
    int sum = a0 + a1 + a2 + a3;
    ts[t] = sum;
    for (int off = 1; off < 256; off <<= 1) {
        __syncthreads();
        int v = (t >= off) ? ts[t - off] : 0;
        __syncthreads();
        ts[t] += v;
    }
    __syncthreads();
    int excl = ts[t] - sum;
    if (base + 4*t + 0 < n) local[base + 4*t + 0] = excl;
    if (base + 4*t + 1 < n) local[base + 4*t + 1] = excl + a0;
    if (base + 4*t + 2 < n) local[base + 4*t + 2] = excl + a0 + a1;
    if (base + 4*t + 3 < n) local[base + 4*t + 3] = excl + a0 + a1 + a2;
    if (t == 255) bsums[blockIdx.x] = ts[255];
}

__global__ void scan_bsums(int* __restrict__ bsums, int nb) {
    __shared__ int ts[256];
    const int t = threadIdx.x;
    int v = (t < nb) ? bsums[t] : 0;
    ts[t] = v;
    for (int off = 1; off < 256; off <<= 1) {
        __syncthreads();
        int u = (t >= off) ? ts[t - off] : 0;
        __syncthreads();
        ts[t] += u;
    }
    __syncthreads();
    if (t < nb) bsums[t] = ts[t] - v;
}

__global__ void scan_add(int* __restrict__ offs, const int* __restrict__ bsums, int n, int e_total) {
    int i = blockIdx.x * blockDim.x + threadIdx.x;
    int stride = gridDim.x * blockDim.x;
    for (; i < n; i += stride) offs[i] += bsums[i >> 10];
    if (blockIdx.x == 0 && threadIdx.x == 0) offs[n] = e_total;
}

__global__ void fill_kernel(const int* __restrict__ src, const int* __restrict__ dst,
                            const int* __restrict__ offs, int* __restrict__ cursor,
                            const float* __restrict__ dinv,
                            int2* __restrict__ csr, int e) {
    int i = blockIdx.x * blockDim.x + threadIdx.x;
    int stride = gridDim.x * blockDim.x;
    for (; i < e; i += stride) {
        int s = src[i], d = dst[i];
        int pos = offs[d] + atomicAdd(&cursor[d], 1);
        int2 rec;
        rec.x = s;
        rec.y = __float_as_int(dinv[s] * dinv[d]);
        csr[pos] = rec;
    }
}

// --- pack W1 (f32 [128][128]) into bf16 B-fragment order --------------------
// b_frag element j of lane (16u+lcol) for (coltile c, kstep t) must hold
// W1[k=32t+8u+j][col=16c+lcol]; pos = ((c*4+t)*64 + lane)*8 + j.
__global__ void packW1_kernel(const float* __restrict__ W1, ushort* __restrict__ W1f) {
    int idx = blockIdx.x * blockDim.x + threadIdx.x;   // 16384 total
    int k = idx >> 7, col = idx & 127;
    int c = col >> 4, lcol = col & 15;
    int t = k >> 5, u = (k >> 3) & 3, j = k & 7;
    int lane = u * 16 + lcol;
    W1f[(size_t)(((c * 4 + t) * 64 + lane) * 8 + j)] = f2bf(W1[idx]);
}

// --- matmul1 via MFMA: xw1b[n x 128] (bf16) = x @ W1 ------------------------
// 256 thr = 4 waves; block does 64 rows; wave w -> rows [64*blk+16w, +16).
// A-frags from global f32 x (converted in-reg); B-frags from LDS (W1f staged).
__global__ __launch_bounds__(256)
void mfma1_kernel(const float* __restrict__ x, const ushort* __restrict__ W1f,
                  ushort* __restrict__ outb, int n) {
    __shared__ ushort bsm[16384];                      // 32 KB, frag order
    const int tid = threadIdx.x;
    // stage W1f linearly: 2048 uint4 / 256 thr = 8 each
    #pragma unroll
    for (int j = 0; j < 8; ++j)
        ((uint4*)bsm)[tid + j * 256] = ((const uint4*)W1f)[tid + j * 256];

    const int w = tid >> 6;
    const int lane = tid & 63;
    const int r = lane & 15;
    const int u = lane >> 4;
    const int row0 = blockIdx.x * 64 + w * 16;
    int arow = row0 + r; if (arow >= n) arow = n - 1;   // clamp for load

    // A fragments: a[t][j] = x[arow][32t + 8u + j], bf16
    bf16x8 afr[4];
    #pragma unroll
    for (int t = 0; t < 4; ++t) {
        const float* px = &x[(size_t)arow * 128 + t * 32 + u * 8];
        f32x4 v0 = *(const f32x4*)px;
        f32x4 v1 = *(const f32x4*)(px + 4);
        bf16x8 a;
        a[0] = (short)f2bf(v0[0]); a[1] = (short)f2bf(v0[1]);
        a[2] = (short)f2bf(v0[2]); a[3] = (short)f2bf(v0[3]);
        a[4] = (short)f2bf(v1[0]); a[5] = (short)f2bf(v1[1]);
        a[6] = (short)f2bf(v1[2]); a[7] = (short)f2bf(v1[3]);
        afr[t] = a;
    }
    __syncthreads();

    f32x4 acc[8];
    #pragma unroll
    for (int c = 0; c < 8; ++c) acc[c] = (f32x4){0.f, 0.f, 0.f, 0.f};

    #pragma unroll
    for (int c = 0; c < 8; ++c) {
        #pragma unroll
        for (int t = 0; t < 4; ++t) {
            bf16x8 b = *(const bf16x8*)&bsm[(size_t)(((c * 4 + t) * 64 + lane) * 8)];
            acc[c] = __builtin_amdgcn_mfma_f32_16x16x32_bf16(afr[t], b, acc[c], 0, 0, 0);
        }
    }

    // D: col = lane&15 (=r), row = 4u + reg
    #pragma unroll
    for (int c = 0; c < 8; ++c) {
        #pragma unroll
        for (int rr = 0; rr < 4; ++rr) {
            int row = row0 + u * 4 + rr;
            if (row < n) outb[(size_t)row * 128 + c * 16 + r] = f2bf(acc[c][rr]);
        }
    }
}

// --- generic small matmul (layer 2): out[n x DOUT] = x[n x 128] @ W ---------
template<int ROWS, int DOUT>
__global__ __launch_bounds__((ROWS/4)*(DOUT/4))
void matmul_kernel(const float* __restrict__ x, const float* __restrict__ W,
                   float* __restrict__ out, int n) {
    constexpr int K = KDIM;
    constexpr int TPB = (ROWS/4) * (DOUT/4);
    __shared__ float xs[ROWS][K];
    __shared__ float ws[K][DOUT];
    const int tid = threadIdx.x;
    const int row0 = blockIdx.x * ROWS;

    for (int idx = tid; idx < K*DOUT/4; idx += TPB)
        ((float4*)ws)[idx] = ((const float4*)W)[idx];
    for (int idx = tid; idx < ROWS*K/4; idx += TPB) {
        int r = idx / (K/4);
        int row = row0 + r;
        float4 v = (row < n) ? ((const float4*)x)[(size_t)row*(K/4) + (idx % (K/4))]
                             : make_float4(0.f, 0.f, 0.f, 0.f);
        ((float4*)xs)[idx] = v;
    }
    __syncthreads();

    const int tc = tid % (DOUT/4);
    const int tr = tid / (DOUT/4);
    float acc[4][4] = {};
    #pragma unroll 4
    for (int k = 0; k < K; k += 4) {
        float xa[4][4], wb[4][4];
        #pragma unroll
        for (int r = 0; r < 4; ++r) {
            float4 v = *(const float4*)&xs[tr*4 + r][k];
            xa[r][0] = v.x; xa[r][1] = v.y; xa[r][2] = v.z; xa[r][3] = v.w;
        }
        #pragma unroll
        for (int kk = 0; kk < 4; ++kk) {
            float4 v = *(const float4*)&ws[k + kk][tc*4];
            wb[kk][0] = v.x; wb[kk][1] = v.y; wb[kk][2] = v.z; wb[kk][3] = v.w;
        }
        #pragma unroll
        for (int r = 0; r < 4; ++r)
            #pragma unroll
            for (int kk = 0; kk < 4; ++kk)
                #pragma unroll
                for (int c = 0; c < 4; ++c)
                    acc[r][c] += xa[r][kk] * wb[kk][c];
    }
    #pragma unroll
    for (int r = 0; r < 4; ++r) {
        int row = row0 + tr*4 + r;
        if (row < n) {
            float4 v = make_float4(acc[r][0], acc[r][1], acc[r][2], acc[r][3]);
            *(float4*)&out[(size_t)row*DOUT + tc*4] = v;
        }
    }
}

// --- aggregation, D=128 over bf16 rows: one wave per node -------------------
__device__ inline void bf2_fma(uint u, float nr, float& a0, float& a1) {
    a0 += __uint_as_float(u << 16) * nr;
    a1 += __uint_as_float(u & 0xffff0000u) * nr;
}

__global__ __launch_bounds__(256)
void agg128_kernel(const ushort* __restrict__ xwb, const int* __restrict__ offs,
                   const int2* __restrict__ csr, const float* __restrict__ dinv,
                   const float* __restrict__ bias, float* __restrict__ out,
                   int n, int do_relu) {
    const int w = threadIdx.x >> 6;
    const int i = blockIdx.x * 4 + w;
    if (i >= n) return;
    const int lane = threadIdx.x & 63;
    const int g = lane >> 4;
    const int q = lane & 15;

    float acc[8] = {};
    const int e0 = offs[i], e1 = offs[i + 1];
    int e = e0 + g;
    for (; e + 4 < e1; e += 8) {
        int2 p0 = csr[e];
        int2 p1 = csr[e + 4];
        uint4 u0 = *(const uint4*)&xwb[(size_t)p0.x * 128 + q * 8];
        uint4 u1 = *(const uint4*)&xwb[(size_t)p1.x * 128 + q * 8];
        float n0 = __int_as_float(p0.y);
        float n1 = __int_as_float(p1.y);
        bf2_fma(u0.x, n0, acc[0], acc[1]);
        bf2_fma(u0.y, n0, acc[2], acc[3]);
        bf2_fma(u0.z, n0, acc[4], acc[5]);
        bf2_fma(u0.w, n0, acc[6], acc[7]);
        bf2_fma(u1.x, n1, acc[0], acc[1]);
        bf2_fma(u1.y, n1, acc[2], acc[3]);
        bf2_fma(u1.z, n1, acc[4], acc[5]);
        bf2_fma(u1.w, n1, acc[6], acc[7]);
    }
    if (e < e1) {
        int2 p = csr[e];
        uint4 u = *(const uint4*)&xwb[(size_t)p.x * 128 + q * 8];
        float nr = __int_as_float(p.y);
        bf2_fma(u.x, nr, acc[0], acc[1]);
        bf2_fma(u.y, nr, acc[2], acc[3]);
        bf2_fma(u.z, nr, acc[4], acc[5]);
        bf2_fma(u.w, nr, acc[6], acc[7]);
    }
    #pragma unroll
    for (int j = 0; j < 8; ++j) {
        acc[j] += __shfl_xor(acc[j], 16, 64);
        acc[j] += __shfl_xor(acc[j], 32, 64);
    }

    if (g == 0) {
        const float di = dinv[i];
        const float s = di * di;
        uint4 su = *(const uint4*)&xwb[(size_t)i * 128 + q * 8];
        bf2_fma(su.x, s, acc[0], acc[1]);
        bf2_fma(su.y, s, acc[2], acc[3]);
        bf2_fma(su.z, s, acc[4], acc[5]);
        bf2_fma(su.w, s, acc[6], acc[7]);
        const float4 b0 = *(const float4*)&bias[q * 8];
        const float4 b1 = *(const float4*)&bias[q * 8 + 4];
        float4 r0, r1;
        r0.x = acc[0] + b0.x; r0.y = acc[1] + b0.y; r0.z = acc[2] + b0.z; r0.w = acc[3] + b0.w;
        r1.x = acc[4] + b1.x; r1.y = acc[5] + b1.y; r1.z = acc[6] + b1.z; r1.w = acc[7] + b1.w;
        if (do_relu) {
            r0.x = fmaxf(r0.x, 0.f); r0.y = fmaxf(r0.y, 0.f);
            r0.z = fmaxf(r0.z, 0.f); r0.w = fmaxf(r0.w, 0.f);
            r1.x = fmaxf(r1.x, 0.f); r1.y = fmaxf(r1.y, 0.f);
            r1.z = fmaxf(r1.z, 0.f); r1.w = fmaxf(r1.w, 0.f);
        }
        *(float4*)&out[(size_t)i * 128 + q * 8] = r0;
        *(float4*)&out[(size_t)i * 128 + q * 8 + 4] = r1;
    }
}

// --- aggregation, D=32 (f32): one wave per node, 8 edges in parallel --------
__global__ __launch_bounds__(256)
void agg32_kernel(const float* __restrict__ xw, const int* __restrict__ offs,
                  const int2* __restrict__ csr, const float* __restrict__ dinv,
                  const float* __restrict__ bias, float* __restrict__ out, int n) {
    const int w = threadIdx.x >> 6;
    const int i = blockIdx.x * 4 + w;
    if (i >= n) return;
    const int lane = threadIdx.x & 63;
    const int g = lane >> 3;
    const int q = lane & 7;

    float4 acc = make_float4(0.f, 0.f, 0.f, 0.f);
    const int e0 = offs[i], e1 = offs[i + 1];
    int e = e0 + g;
    for (; e + 8 < e1; e += 16) {
        int2 p0 = csr[e];
        int2 p1 = csr[e + 8];
        const float4 v0 = *(const float4*)&xw[(size_t)p0.x * 32 + q * 4];
        const float4 v1 = *(const float4*)&xw[(size_t)p1.x * 32 + q * 4];
        const float n0 = __int_as_float(p0.y);
        const float n1 = __int_as_float(p1.y);
        acc.x += v0.x * n0; acc.y += v0.y * n0; acc.z += v0.z * n0; acc.w += v0.w * n0;
        acc.x += v1.x * n1; acc.y += v1.y * n1; acc.z += v1.z * n1; acc.w += v1.w * n1;
    }
    if (e < e1) {
        int2 p = csr[e];
        const float4 v = *(const float4*)&xw[(size_t)p.x * 32 + q * 4];
        const float nr = __int_as_float(p.y);
        acc.x += v.x * nr; acc.y += v.y * nr; acc.z += v.z * nr; acc.w += v.w * nr;
    }
    #pragma unroll
    for (int m = 8; m <= 32; m <<= 1) {
        acc.x += __shfl_xor(acc.x, m, 64);
        acc.y += __shfl_xor(acc.y, m, 64);
        acc.z += __shfl_xor(acc.z, m, 64);
        acc.w += __shfl_xor(acc.w, m, 64);
    }

    if (g == 0) {
        const float di = dinv[i];
        const float s = di * di;
        const float4 sv = *(const float4*)&xw[(size_t)i * 32 + q * 4];
        const float4 b  = *(const float4*)&bias[q * 4];
        float4 r;
        r.x = acc.x + sv.x * s + b.x;
        r.y = acc.y + sv.y * s + b.y;
        r.z = acc.z + sv.z * s + b.z;
        r.w = acc.w + sv.w * s + b.w;
        *(float4*)&out[(size_t)i * 32 + q * 4] = r;
    }
}

extern "C" void kernel_launch(void* const* d_in, const int* in_sizes, int n_in,
                              void* d_out, int out_size, void* d_ws, size_t ws_size,
                              hipStream_t stream) {
    const int n = in_sizes[0] / KDIM;      // 100000
    const int e = in_sizes[1] / 2;         // 1600000

    const float* x  = (const float*)d_in[0];
    const int*   ei = (const int*)d_in[1];
    const int*   src = ei;
    const int*   dst = ei + e;
    const float* W1 = (const float*)d_in[2];
    const float* b1 = (const float*)d_in[3];
    const float* W2 = (const float*)d_in[4];
    const float* b2 = (const float*)d_in[5];
    float* out = (float*)d_out;

    // workspace carve (256B aligned)
    char* p = (char*)d_ws;
    auto alloc = [&](size_t bytes) { char* q = p; p += (bytes + 255) & ~(size_t)255; return q; };
    float*  dinv   = (float*)alloc((size_t)n * 4);
    int*    counts = (int*)  alloc((size_t)n * 4);
    int*    cursor = (int*)  alloc((size_t)n * 4);
    int*    offs   = (int*)  alloc((size_t)(n + 1) * 4);
    int*    bsums  = (int*)  alloc(1024 * 4);
    int2*   csr    = (int2*) alloc((size_t)e * 8);
    ushort* W1f    = (ushort*)alloc((size_t)128 * 128 * 2);
    ushort* xw1b   = (ushort*)alloc((size_t)n * 128 * 2);
    float*  h      = (float*)alloc((size_t)n * 128 * 4);
    float*  xw2    = (float*)alloc((size_t)n * 32 * 4);

    const int nb_scan = (n + 1023) / 1024;

    init_counts<<<256, 256, 0, stream>>>(counts, cursor, n);
    count_kernel<<<1024, 256, 0, stream>>>(dst, counts, e);
    dinv_kernel<<<(n + 255) / 256, 256, 0, stream>>>(counts, dinv, n);
    scan_partial<<<nb_scan, 256, 0, stream>>>(counts, offs, bsums, n);
    scan_bsums<<<1, 256, 0, stream>>>(bsums, nb_scan);
    scan_add<<<512, 256, 0, stream>>>(offs, bsums, n, e);
    fill_kernel<<<1024, 256, 0, stream>>>(src, dst, offs, cursor, dinv, csr, e);
    packW1_kernel<<<64, 256, 0, stream>>>(W1, W1f);

    // layer 1: xw1b = bf16(x@W1) via MFMA ; h = relu(agg(xw1b) + b1)
    mfma1_kernel<<<(n + 63) / 64, 256, 0, stream>>>(x, W1f, xw1b, n);
    agg128_kernel<<<(n + 3) / 4, 256, 0, stream>>>(xw1b, offs, csr, dinv, b1, h, n, 1);

    // layer 2: xw2 = h@W2 ; out = agg(xw2) + b2
    matmul_kernel<64, 32><<<(n + 63) / 64, 128, 0, stream>>>(h, W2, xw2, n);
    agg32_kernel<<<(n + 3) / 4, 256, 0, stream>>>(xw2, offs, csr, dinv, b2, out, n);
}